// Round 11
// baseline (344.510 us; speedup 1.0000x reference)
//
#include <hip/hip_runtime.h>
#include <hip/hip_bf16.h>
#include <cstdint>
#include <cstddef>

// Problem constants
#define B_ 8
#define S_ 1024
#define H_ 16
#define E_ 64
#define D_ 1024      // embed dim

typedef unsigned short u16;
typedef short s16x8 __attribute__((ext_vector_type(8)));
typedef float f32x4 __attribute__((ext_vector_type(4)));

// fp32 -> bf16, round-to-nearest-even
__device__ __forceinline__ u16 f2b(float f) {
  union { float f; unsigned u; } v; v.f = f;
  unsigned u = v.u;
  return (u16)((u + 0x7FFFu + ((u >> 16) & 1u)) >> 16);
}

// async global->LDS, 16B per lane. LDS dest is wave-uniform base + lane*16.
__device__ __forceinline__ void gload16(const void* g, void* lds) {
  __builtin_amdgcn_global_load_lds(
      (const __attribute__((address_space(1))) void*)g,
      (__attribute__((address_space(3))) void*)lds, 16, 0, 0);
}

// LDS-only barrier: drain own DS ops, raw s_barrier, fenced (rule #18).
#define BARL() do {                                          \
  asm volatile("s_waitcnt lgkmcnt(0)" ::: "memory");         \
  __builtin_amdgcn_sched_barrier(0);                         \
  __builtin_amdgcn_s_barrier();                              \
  __builtin_amdgcn_sched_barrier(0);                         \
  asm volatile("" ::: "memory");                             \
} while (0)

// ---------------- kernel 1: merged x->bf16 cvt + WbT build ----------------
__global__ void k_prep(const float* __restrict__ x, u16* __restrict__ xb,
                       const float* __restrict__ Wq, const float* __restrict__ Wk,
                       const float* __restrict__ Wv, u16* __restrict__ wbt) {
  if (blockIdx.x < 4096) {
    size_t i = ((size_t)blockIdx.x * 256 + threadIdx.x) * 8;
    float4 a = *(const float4*)(x + i);
    float4 b = *(const float4*)(x + i + 4);
    uint4 o;
    o.x = f2b(a.x) | ((unsigned)f2b(a.y) << 16);
    o.y = f2b(a.z) | ((unsigned)f2b(a.w) << 16);
    o.z = f2b(b.x) | ((unsigned)f2b(b.y) << 16);
    o.w = f2b(b.z) | ((unsigned)f2b(b.w) << 16);
    *(uint4*)(xb + i) = o;
    return;
  }
  __shared__ u16 T[64][65];
  int bid = blockIdx.x - 4096;           // 0..767
  int d0 = (bid & 15) * 64;
  int mh = bid >> 4;
  int mat = mh >> 4, h = mh & 15;
  const float* W = (mat == 0) ? Wq : (mat == 1) ? Wk : Wv;
  int tid = threadIdx.x;
#pragma unroll
  for (int rep = 0; rep < 4; rep++) {
    int dl = rep * 16 + (tid >> 4);
    int e0 = (tid & 15) * 4;
    float4 v = *(const float4*)(W + (size_t)h * (D_ * E_) + (size_t)(d0 + dl) * E_ + e0);
    T[dl][e0] = f2b(v.x); T[dl][e0 + 1] = f2b(v.y);
    T[dl][e0 + 2] = f2b(v.z); T[dl][e0 + 3] = f2b(v.w);
  }
  __syncthreads();
#pragma unroll
  for (int rep = 0; rep < 4; rep++) {
    int el = rep * 16 + (tid >> 4);
    int dl0 = (tid & 15) * 4;
    ushort4 o;
    o.x = T[dl0][el]; o.y = T[dl0 + 1][el]; o.z = T[dl0 + 2][el]; o.w = T[dl0 + 3][el];
    int n = mat * 1024 + h * 64 + el;
    *(ushort4*)(wbt + (size_t)n * D_ + d0 + dl0) = o;
  }
}

// ---------------- kernel 2: QKV GEMM, XCD-chunked, V written pre-transposed ----
__global__ __launch_bounds__(256) void k_qkv(
    const u16* __restrict__ xb, const u16* __restrict__ wbt,
    const float* __restrict__ bq, const float* __restrict__ bk, const float* __restrict__ bv,
    u16* __restrict__ Qb, u16* __restrict__ Kb, u16* __restrict__ Vt) {
  __shared__ u16 As[128 * 64];
  __shared__ u16 Bs[128 * 64];
  int tid = threadIdx.x, l = tid & 63, w = tid >> 6;
  int bid = blockIdx.x;
  int xcd = bid & 7, i = bid >> 3;
  int m0 = (xcd * 8 + i / 24) * 128;
  int n0 = (i % 24) * 128;
  int wm = w >> 1, wn = w & 1;
  int rl = l & 15, kg = l >> 4;
  f32x4 acc[4][4] = {};
  for (int k0 = 0; k0 < D_; k0 += 64) {
#pragma unroll
    for (int i2 = 0; i2 < 4; i2++) {
      int ci = w * 4 + i2;
      int r = ci * 8 + (l >> 3);
      int c = (l & 7) ^ (r & 7);
      gload16(xb  + (size_t)(m0 + r) * D_ + k0 + c * 8, (char*)As + ci * 1024);
      gload16(wbt + (size_t)(n0 + r) * D_ + k0 + c * 8, (char*)Bs + ci * 1024);
    }
    __syncthreads();
#pragma unroll
    for (int kk = 0; kk < 2; kk++) {
      s16x8 af[4], bfr[4];
      int chunk = kk * 4 + kg;
#pragma unroll
      for (int fm = 0; fm < 4; fm++) {
        int r = wm * 64 + fm * 16 + rl;
        af[fm] = *(const s16x8*)(As + r * 64 + ((chunk ^ (r & 7)) * 8));
      }
#pragma unroll
      for (int fn = 0; fn < 4; fn++) {
        int r = wn * 64 + fn * 16 + rl;
        bfr[fn] = *(const s16x8*)(Bs + r * 64 + ((chunk ^ (r & 7)) * 8));
      }
#pragma unroll
      for (int fm = 0; fm < 4; fm++)
#pragma unroll
        for (int fn = 0; fn < 4; fn++)
          acc[fm][fn] = __builtin_amdgcn_mfma_f32_16x16x32_bf16(af[fm], bfr[fn], acc[fm][fn], 0, 0, 0);
    }
    __syncthreads();
  }
#pragma unroll
  for (int fn = 0; fn < 4; fn++) {
    int n = n0 + wn * 64 + fn * 16 + rl;
    int mat = n >> 10, h = (n >> 6) & 15, e = n & 63;
    const float* bias = (mat == 0) ? bq : (mat == 1) ? bk : bv;
    float bval = bias[h * 64 + e];
    if (mat == 2) {
#pragma unroll
      for (int fm = 0; fm < 4; fm++) {
        int sq = m0 + wm * 64 + fm * 16 + kg * 4;
        int bb = sq >> 10, s = sq & 1023;
        ushort4 o;
        o.x = f2b(acc[fm][fn][0] + bval);
        o.y = f2b(acc[fm][fn][1] + bval);
        o.z = f2b(acc[fm][fn][2] + bval);
        o.w = f2b(acc[fm][fn][3] + bval);
        *(ushort4*)(Vt + ((size_t)((h * B_ + bb) * E_ + e) << 10) + s) = o;
      }
    } else {
      u16* dst = (mat == 0) ? Qb : Kb;
#pragma unroll
      for (int fm = 0; fm < 4; fm++)
#pragma unroll
        for (int j = 0; j < 4; j++) {
          int m = m0 + wm * 64 + fm * 16 + kg * 4 + j;
          int bb = m >> 10, s = m & 1023;
          dst[(size_t)((h * B_ + bb) * S_ + s) * E_ + e] = f2b(acc[fm][fn][j] + bval);
        }
    }
  }
}

// ---------------- kernel 3: fused attention v3 — half-resident K/V, 2 blocks/CU ----
// Block = 32 q-rows, 4 waves, LDS 77.5KB -> 2 blocks/CU (sibling overlap hides
// drains). K as two 64KB halves: barrier-free 8-chunk QK sweep per half, one
// full drain at the swap. V likewise; one mid-PV drain (only V loads outstanding:
// att stores deferred to kernel end, fire-and-forget, drain under next block).
__global__ __launch_bounds__(256, 2) void f_attn(
    const u16* __restrict__ Qb, const u16* __restrict__ Kb, const u16* __restrict__ Vt,
    const float* __restrict__ x, float* __restrict__ att, float* __restrict__ out) {
  __shared__ u16 KV[512 * 64];      // 64KB: K half [512t][64e] rows 128B; later V half [64e][512t] rows 1024B
  __shared__ u16 Ab[2][32 * 64];    // 8KB P-bf16 chunk dbuf [q 32][t 64]
  __shared__ u16 Qlds[32 * 64];     // 4KB
  __shared__ float red[3][32][4];   // 1.5KB cross-wave reduce

  int p = blockIdx.x;
  int L = (p & 7) * 512 + (p >> 3);    // XCD-chunked: 512 consecutive units per XCD
  int hb = L >> 5, mblk = L & 31;
  int m0 = mblk * 32;
  int tid = threadIdx.x, l = tid & 63, w = tid >> 6;   // 4 waves
  int rl = l & 15, kg = l >> 4;

  const u16* Qp = Qb + (size_t)hb * (S_ * E_) + (size_t)m0 * E_;
  const u16* Kp = Kb + (size_t)hb * (S_ * E_);
  const u16* Vp = Vt + (size_t)hb * (S_ * E_);

  // ---- stage Q (32x64) + K half 0 (rows 0..511) ----
  {
    int r = w * 8 + (l >> 3), c = (l & 7) ^ (r & 7);
    gload16(Qp + (size_t)r * E_ + c * 8, (char*)Qlds + w * 1024);
  }
#pragma unroll
  for (int i = 0; i < 16; i++) {
    int ci = w * 16 + i;
    int r = ci * 8 + (l >> 3), c = (l & 7) ^ (r & 7);
    gload16(Kp + (size_t)r * E_ + c * 8, (char*)KV + ci * 1024);
  }
  __syncthreads();   // full drain: Q + K-half0 in LDS

  s16x8 af[2][2];
#pragma unroll
  for (int fm = 0; fm < 2; fm++)
#pragma unroll
    for (int kk = 0; kk < 2; kk++) {
      int q = fm * 16 + rl, ch = kk * 4 + kg;
      af[fm][kk] = *(const s16x8*)((const char*)Qlds + q * 128 + ((ch ^ (q & 7)) * 16));
    }

  f32x4 acc[2][16];
#pragma unroll
  for (int fm = 0; fm < 2; fm++)
#pragma unroll
    for (int ct = 0; ct < 16; ct++)
#pragma unroll
      for (int j = 0; j < 4; j++) acc[fm][ct][j] = 0.f;

  // ---- QK half 0: barrier-free sweep, t = ct*64 + w*16 + rl ----
#pragma unroll
  for (int ct = 0; ct < 8; ct++) {
    s16x8 bf[2];
#pragma unroll
    for (int kk = 0; kk < 2; kk++) {
      int r = ct * 64 + w * 16 + rl, ch = kk * 4 + kg;
      bf[kk] = *(const s16x8*)((const char*)KV + r * 128 + ((ch ^ (r & 7)) * 16));
    }
#pragma unroll
    for (int fm = 0; fm < 2; fm++)
#pragma unroll
      for (int kk = 0; kk < 2; kk++)
        acc[fm][ct] = __builtin_amdgcn_mfma_f32_16x16x32_bf16(af[fm][kk], bf[kk], acc[fm][ct], 0, 0, 0);
  }
  BARL();   // all waves done reading K-half0

  // ---- stage K half 1 (rows 512..1023), full drain (sibling-overlapped) ----
#pragma unroll
  for (int i = 0; i < 16; i++) {
    int ci = w * 16 + i;
    int r = ci * 8 + (l >> 3), c = (l & 7) ^ (r & 7);
    gload16(Kp + (size_t)(512 + r) * E_ + c * 8, (char*)KV + ci * 1024);
  }
  __syncthreads();

  // ---- QK half 1 ----
#pragma unroll
  for (int ct = 0; ct < 8; ct++) {
    s16x8 bf[2];
#pragma unroll
    for (int kk = 0; kk < 2; kk++) {
      int r = ct * 64 + w * 16 + rl, ch = kk * 4 + kg;
      bf[kk] = *(const s16x8*)((const char*)KV + r * 128 + ((ch ^ (r & 7)) * 16));
    }
#pragma unroll
    for (int fm = 0; fm < 2; fm++)
#pragma unroll
      for (int kk = 0; kk < 2; kk++)
        acc[fm][8 + ct] = __builtin_amdgcn_mfma_f32_16x16x32_bf16(af[fm][kk], bf[kk], acc[fm][8 + ct], 0, 0, 0);
  }
  BARL();   // all K reads done -> safe to overwrite KV with V half 0

  // ---- issue V half 0 ([64e][512t], 1024B rows; in flight through softmax) ----
#pragma unroll
  for (int i = 0; i < 16; i++) {
    int e = w * 16 + i;
    int c = (l & ~7) | ((l & 7) ^ (e & 7));
    gload16(Vp + (size_t)e * S_ + c * 8, (char*)KV + e * 1024);
  }

  // ---- x prefetch (lands under softmax) ----
  int h = hb >> 3, bb = hb & 7;
  float xv[2][4];
#pragma unroll
  for (int fm = 0; fm < 2; fm++)
#pragma unroll
    for (int j = 0; j < 4; j++) {
      int mq = m0 + fm * 16 + kg * 4 + j;
      int e = h * 64 + w * 16 + rl;
      xv[fm][j] = x[(((size_t)bb * S_ + mq) << 10) + e];
    }

  // ---- softmax (scale 1/32 folded into exp); lgkm-only barriers ----
  float mx[2][4], Z[2][4], Z2[2][4];
#pragma unroll
  for (int fm = 0; fm < 2; fm++)
#pragma unroll
    for (int j = 0; j < 4; j++) {
      float m = acc[fm][0][j];
#pragma unroll
      for (int ct = 1; ct < 16; ct++) m = fmaxf(m, acc[fm][ct][j]);
#pragma unroll
      for (int off = 8; off >= 1; off >>= 1) m = fmaxf(m, __shfl_xor(m, off));
      mx[fm][j] = m;
    }
  if (rl == 0) {
#pragma unroll
    for (int fm = 0; fm < 2; fm++)
#pragma unroll
      for (int j = 0; j < 4; j++) red[0][fm * 16 + kg * 4 + j][w] = mx[fm][j];
  }
  BARL();
#pragma unroll
  for (int fm = 0; fm < 2; fm++)
#pragma unroll
    for (int j = 0; j < 4; j++) {
      f32x4 r4 = *(const f32x4*)&red[0][fm * 16 + kg * 4 + j][0];
      mx[fm][j] = fmaxf(fmaxf(r4[0], r4[1]), fmaxf(r4[2], r4[3]));
    }
#pragma unroll
  for (int fm = 0; fm < 2; fm++)
#pragma unroll
    for (int j = 0; j < 4; j++) {
      float s = 0.f;
#pragma unroll
      for (int ct = 0; ct < 16; ct++) {
        float e = __expf((acc[fm][ct][j] - mx[fm][j]) * 0.03125f);
        acc[fm][ct][j] = e;
        s += e;
      }
#pragma unroll
      for (int off = 8; off >= 1; off >>= 1) s += __shfl_xor(s, off);
      Z[fm][j] = s;
    }
  if (rl == 0) {
#pragma unroll
    for (int fm = 0; fm < 2; fm++)
#pragma unroll
      for (int j = 0; j < 4; j++) red[1][fm * 16 + kg * 4 + j][w] = Z[fm][j];
  }
  BARL();
#pragma unroll
  for (int fm = 0; fm < 2; fm++)
#pragma unroll
    for (int j = 0; j < 4; j++) {
      f32x4 r4 = *(const f32x4*)&red[1][fm * 16 + kg * 4 + j][0];
      Z[fm][j] = r4[0] + r4[1] + r4[2] + r4[3];
    }
  // threshold: keep e >= 0.001*Z (<=> p >= 0.001), re-sum survivors
#pragma unroll
  for (int fm = 0; fm < 2; fm++)
#pragma unroll
    for (int j = 0; j < 4; j++) {
      float thr = 0.001f * Z[fm][j];
      float s = 0.f;
#pragma unroll
      for (int ct = 0; ct < 16; ct++) {
        float e = acc[fm][ct][j];
        e = (e >= thr) ? e : 0.f;
        acc[fm][ct][j] = e;
        s += e;
      }
#pragma unroll
      for (int off = 8; off >= 1; off >>= 1) s += __shfl_xor(s, off);
      Z2[fm][j] = s;
    }
  if (rl == 0) {
#pragma unroll
    for (int fm = 0; fm < 2; fm++)
#pragma unroll
      for (int j = 0; j < 4; j++) red[2][fm * 16 + kg * 4 + j][w] = Z2[fm][j];
  }
  BARL();
#pragma unroll
  for (int fm = 0; fm < 2; fm++)
#pragma unroll
    for (int j = 0; j < 4; j++) {
      f32x4 r4 = *(const f32x4*)&red[2][fm * 16 + kg * 4 + j][0];
      float z2 = r4[0] + r4[1] + r4[2] + r4[3];
      float inv = 1.f / (z2 + 1e-12f * Z[fm][j]);  // == p/(sum_kept_p + 1e-12)
#pragma unroll
      for (int ct = 0; ct < 16; ct++) acc[fm][ct][j] *= inv;
    }

  // ---- retire V-half0 + x loads (cross-wave ordering via next barrier) ----
  asm volatile("s_waitcnt vmcnt(0)" ::: "memory");
  __builtin_amdgcn_sched_barrier(0);

  // ---- PV prologue: publish chunk 0 ----
#pragma unroll
  for (int fm = 0; fm < 2; fm++)
#pragma unroll
    for (int j = 0; j < 4; j++) {
      int m = fm * 16 + kg * 4 + j;
      int tl = w * 16 + rl;
      *(u16*)((char*)Ab[0] + m * 128 + (((tl >> 3) ^ (m & 7)) * 16) + (tl & 7) * 2)
          = f2b(acc[fm][0][j]);
    }
  BARL();

  // ---- PV loop: chunk ct; V-half swap after ct=7 ----
  f32x4 acc2[2];
#pragma unroll
  for (int fm = 0; fm < 2; fm++)
#pragma unroll
    for (int j = 0; j < 4; j++) acc2[fm][j] = 0.f;

#pragma unroll
  for (int ct = 0; ct < 16; ct++) {
    s16x8 a2[2][2], b2[2];
#pragma unroll
    for (int kk = 0; kk < 2; kk++) {
      int ch = kk * 4 + kg;
#pragma unroll
      for (int fm = 0; fm < 2; fm++) {
        int rA = fm * 16 + rl;
        a2[fm][kk] = *(const s16x8*)((const char*)Ab[ct & 1] + rA * 128 + ((ch ^ (rA & 7)) * 16));
      }
      {
        int e = w * 16 + rl;
        b2[kk] = *(const s16x8*)((const char*)KV + e * 1024 + (ct & 7) * 128 + ((ch ^ (e & 7)) * 16));
      }
    }
    if (ct < 15) {  // publish next chunk into the other buffer
#pragma unroll
      for (int fm = 0; fm < 2; fm++)
#pragma unroll
        for (int j = 0; j < 4; j++) {
          int m = fm * 16 + kg * 4 + j;
          int tl = w * 16 + rl;
          *(u16*)((char*)Ab[(ct + 1) & 1] + m * 128 + (((tl >> 3) ^ (m & 7)) * 16) + (tl & 7) * 2)
              = f2b(acc[fm][ct + 1][j]);
        }
    }
    __builtin_amdgcn_s_setprio(1);
#pragma unroll
    for (int fm = 0; fm < 2; fm++)
#pragma unroll
      for (int kk = 0; kk < 2; kk++)
        acc2[fm] = __builtin_amdgcn_mfma_f32_16x16x32_bf16(a2[fm][kk], b2[kk], acc2[fm], 0, 0, 0);
    __builtin_amdgcn_s_setprio(0);
    BARL();
    if (ct == 7) {
      // swap V halves: the BARL above guarantees all half-0 reads are done
#pragma unroll
      for (int i = 0; i < 16; i++) {
        int e = w * 16 + i;
        int c = (l & ~7) | ((l & 7) ^ (e & 7));
        gload16(Vp + (size_t)e * S_ + 512 + c * 8, (char*)KV + e * 1024);
      }
      asm volatile("s_waitcnt vmcnt(0)" ::: "memory");   // only V loads outstanding
      __builtin_amdgcn_sched_barrier(0);
      BARL();
    }
  }

  // ---- att fp32 stores: ALL deferred here, fire-and-forget (drain under next block) ----
  float* attp = att + ((size_t)hb << 20) + ((size_t)m0 << 10);
#pragma unroll
  for (int fm = 0; fm < 2; fm++)
#pragma unroll
    for (int j = 0; j < 4; j++) {
      int m = fm * 16 + kg * 4 + j;
#pragma unroll
      for (int ct = 0; ct < 16; ct++)
        attp[((size_t)m << 10) + ct * 64 + w * 16 + rl] = acc[fm][ct][j];
    }

  // ---- epilogue: out = xv + latent (pure stores) ----
#pragma unroll
  for (int fm = 0; fm < 2; fm++)
#pragma unroll
    for (int j = 0; j < 4; j++) {
      int mq = m0 + fm * 16 + kg * 4 + j;
      int e = h * 64 + w * 16 + rl;
      size_t idx = (((size_t)bb * S_ + mq) << 10) + e;
      out[idx] = xv[fm][j] + acc2[fm][j];
    }
}

extern "C" void kernel_launch(void* const* d_in, const int* in_sizes, int n_in,
                              void* d_out, int out_size, void* d_ws, size_t ws_size,
                              hipStream_t stream) {
  const float* x  = (const float*)d_in[0];
  const float* Wq = (const float*)d_in[1];
  const float* bq = (const float*)d_in[2];
  const float* Wk = (const float*)d_in[3];
  const float* bk = (const float*)d_in[4];
  const float* Wv = (const float*)d_in[5];
  const float* bv = (const float*)d_in[6];
  float* xres = (float*)d_out;
  float* att  = xres + (size_t)B_ * S_ * D_;

  char* ws = (char*)d_ws;
  u16* xb  = (u16*)(ws);                  // 16 MB
  u16* wbt = (u16*)(ws + 16777216);       //  6 MB
  u16* Qb  = (u16*)(ws + 23068672);       // 16 MB
  u16* Kb  = (u16*)(ws + 39845888);       // 16 MB
  u16* Vt  = (u16*)(ws + 56623104);       // 16 MB, [h][b][e][s]

  k_prep  <<<dim3(4864), dim3(256), 0, stream>>>(x, xb, Wq, Wk, Wv, wbt);
  k_qkv   <<<dim3(1536), dim3(256), 0, stream>>>(xb, wbt, bq, bk, bv, Qb, Kb, Vt);
  f_attn  <<<dim3(4096), dim3(256), 0, stream>>>(Qb, Kb, Vt, x, att, xres);
}

// Round 12
// 287.444 us; speedup vs baseline: 1.1985x; 1.1985x over previous
//
#include <hip/hip_runtime.h>
#include <hip/hip_bf16.h>
#include <cstdint>
#include <cstddef>

// Problem constants
#define B_ 8
#define S_ 1024
#define H_ 16
#define E_ 64
#define D_ 1024      // embed dim

typedef unsigned short u16;
typedef short s16x8 __attribute__((ext_vector_type(8)));
typedef float f32x4 __attribute__((ext_vector_type(4)));

// fp32 -> bf16, round-to-nearest-even
__device__ __forceinline__ u16 f2b(float f) {
  union { float f; unsigned u; } v; v.f = f;
  unsigned u = v.u;
  return (u16)((u + 0x7FFFu + ((u >> 16) & 1u)) >> 16);
}

// async global->LDS, 16B per lane. LDS dest is wave-uniform base + lane*16.
__device__ __forceinline__ void gload16(const void* g, void* lds) {
  __builtin_amdgcn_global_load_lds(
      (const __attribute__((address_space(1))) void*)g,
      (__attribute__((address_space(3))) void*)lds, 16, 0, 0);
}

// LDS-only barrier: drain own DS ops, raw s_barrier, fenced against compiler
// motion (rule #18: sched_barrier after inline-asm waitcnt).
#define BARL() do {                                          \
  asm volatile("s_waitcnt lgkmcnt(0)" ::: "memory");         \
  __builtin_amdgcn_sched_barrier(0);                         \
  __builtin_amdgcn_s_barrier();                              \
  __builtin_amdgcn_sched_barrier(0);                         \
  asm volatile("" ::: "memory");                             \
} while (0)

// ---------------- kernel 1: merged x->bf16 cvt + WbT build ----------------
__global__ void k_prep(const float* __restrict__ x, u16* __restrict__ xb,
                       const float* __restrict__ Wq, const float* __restrict__ Wk,
                       const float* __restrict__ Wv, u16* __restrict__ wbt) {
  if (blockIdx.x < 4096) {
    size_t i = ((size_t)blockIdx.x * 256 + threadIdx.x) * 8;
    float4 a = *(const float4*)(x + i);
    float4 b = *(const float4*)(x + i + 4);
    uint4 o;
    o.x = f2b(a.x) | ((unsigned)f2b(a.y) << 16);
    o.y = f2b(a.z) | ((unsigned)f2b(a.w) << 16);
    o.z = f2b(b.x) | ((unsigned)f2b(b.y) << 16);
    o.w = f2b(b.z) | ((unsigned)f2b(b.w) << 16);
    *(uint4*)(xb + i) = o;
    return;
  }
  __shared__ u16 T[64][65];
  int bid = blockIdx.x - 4096;           // 0..767
  int d0 = (bid & 15) * 64;
  int mh = bid >> 4;
  int mat = mh >> 4, h = mh & 15;
  const float* W = (mat == 0) ? Wq : (mat == 1) ? Wk : Wv;
  int tid = threadIdx.x;
#pragma unroll
  for (int rep = 0; rep < 4; rep++) {
    int dl = rep * 16 + (tid >> 4);
    int e0 = (tid & 15) * 4;
    float4 v = *(const float4*)(W + (size_t)h * (D_ * E_) + (size_t)(d0 + dl) * E_ + e0);
    T[dl][e0] = f2b(v.x); T[dl][e0 + 1] = f2b(v.y);
    T[dl][e0 + 2] = f2b(v.z); T[dl][e0 + 3] = f2b(v.w);
  }
  __syncthreads();
#pragma unroll
  for (int rep = 0; rep < 4; rep++) {
    int el = rep * 16 + (tid >> 4);
    int dl0 = (tid & 15) * 4;
    ushort4 o;
    o.x = T[dl0][el]; o.y = T[dl0 + 1][el]; o.z = T[dl0 + 2][el]; o.w = T[dl0 + 3][el];
    int n = mat * 1024 + h * 64 + el;
    *(ushort4*)(wbt + (size_t)n * D_ + d0 + dl0) = o;
  }
}

// ---------------- kernel 2: QKV GEMM, XCD-chunked, V written pre-transposed ----
__global__ __launch_bounds__(256) void k_qkv(
    const u16* __restrict__ xb, const u16* __restrict__ wbt,
    const float* __restrict__ bq, const float* __restrict__ bk, const float* __restrict__ bv,
    u16* __restrict__ Qb, u16* __restrict__ Kb, u16* __restrict__ Vt) {
  __shared__ u16 As[128 * 64];
  __shared__ u16 Bs[128 * 64];
  int tid = threadIdx.x, l = tid & 63, w = tid >> 6;
  int bid = blockIdx.x;
  int xcd = bid & 7, i = bid >> 3;
  int m0 = (xcd * 8 + i / 24) * 128;
  int n0 = (i % 24) * 128;
  int wm = w >> 1, wn = w & 1;
  int rl = l & 15, kg = l >> 4;
  f32x4 acc[4][4] = {};
  for (int k0 = 0; k0 < D_; k0 += 64) {
#pragma unroll
    for (int i2 = 0; i2 < 4; i2++) {
      int ci = w * 4 + i2;
      int r = ci * 8 + (l >> 3);
      int c = (l & 7) ^ (r & 7);
      gload16(xb  + (size_t)(m0 + r) * D_ + k0 + c * 8, (char*)As + ci * 1024);
      gload16(wbt + (size_t)(n0 + r) * D_ + k0 + c * 8, (char*)Bs + ci * 1024);
    }
    __syncthreads();
#pragma unroll
    for (int kk = 0; kk < 2; kk++) {
      s16x8 af[4], bfr[4];
      int chunk = kk * 4 + kg;
#pragma unroll
      for (int fm = 0; fm < 4; fm++) {
        int r = wm * 64 + fm * 16 + rl;
        af[fm] = *(const s16x8*)(As + r * 64 + ((chunk ^ (r & 7)) * 8));
      }
#pragma unroll
      for (int fn = 0; fn < 4; fn++) {
        int r = wn * 64 + fn * 16 + rl;
        bfr[fn] = *(const s16x8*)(Bs + r * 64 + ((chunk ^ (r & 7)) * 8));
      }
#pragma unroll
      for (int fm = 0; fm < 4; fm++)
#pragma unroll
        for (int fn = 0; fn < 4; fn++)
          acc[fm][fn] = __builtin_amdgcn_mfma_f32_16x16x32_bf16(af[fm], bfr[fn], acc[fm][fn], 0, 0, 0);
    }
    __syncthreads();
  }
#pragma unroll
  for (int fn = 0; fn < 4; fn++) {
    int n = n0 + wn * 64 + fn * 16 + rl;
    int mat = n >> 10, h = (n >> 6) & 15, e = n & 63;
    const float* bias = (mat == 0) ? bq : (mat == 1) ? bk : bv;
    float bval = bias[h * 64 + e];
    if (mat == 2) {
#pragma unroll
      for (int fm = 0; fm < 4; fm++) {
        int sq = m0 + wm * 64 + fm * 16 + kg * 4;
        int bb = sq >> 10, s = sq & 1023;
        ushort4 o;
        o.x = f2b(acc[fm][fn][0] + bval);
        o.y = f2b(acc[fm][fn][1] + bval);
        o.z = f2b(acc[fm][fn][2] + bval);
        o.w = f2b(acc[fm][fn][3] + bval);
        *(ushort4*)(Vt + ((size_t)((h * B_ + bb) * E_ + e) << 10) + s) = o;
      }
    } else {
      u16* dst = (mat == 0) ? Qb : Kb;
#pragma unroll
      for (int fm = 0; fm < 4; fm++)
#pragma unroll
        for (int j = 0; j < 4; j++) {
          int m = m0 + wm * 64 + fm * 16 + kg * 4 + j;
          int bb = m >> 10, s = m & 1023;
          dst[(size_t)((h * B_ + bb) * S_ + s) * E_ + e] = f2b(acc[fm][fn][j] + bval);
        }
    }
  }
}

// ---------------- kernel 3: fused attention, K/V LDS-resident (round-10 proven) ----
__global__ __launch_bounds__(512, 2) void f_attn(
    const u16* __restrict__ Qb, const u16* __restrict__ Kb, const u16* __restrict__ Vt,
    const float* __restrict__ x, float* __restrict__ att, float* __restrict__ out) {
  __shared__ u16 Qlds[64 * 64];        // 8 KB
  __shared__ u16 KV[1024 * 64];        // 128 KB: K panel, later V^T panel
  __shared__ u16 Ab[2][64 * 64];       // 16 KB att-bf16 chunk dbuf
  __shared__ float red[3][64][4];      // 3 KB cross-wave reduce

  int p = blockIdx.x;
  int L = (p & 7) * 256 + (p >> 3);    // XCD-chunked: 16 consecutive hb per XCD
  int hb = L >> 4, mblk = L & 15;
  int m0 = mblk * 64;
  int tid = threadIdx.x, l = tid & 63, w = tid >> 6;  // 8 waves
  int rl = l & 15, kg = l >> 4;
  int rh = w >> 2, cq = w & 3;   // QK: row-half, col-quarter

  const u16* Qp = Qb + (size_t)hb * (S_ * E_) + (size_t)m0 * E_;
  const u16* Kp = Kb + (size_t)hb * (S_ * E_);
  const u16* Vp = Vt + (size_t)hb * (S_ * E_);

  // ---- stage Q (64x64) + FULL K panel (1024x64) ----
  {
    int r = w * 8 + (l >> 3), c = (l & 7) ^ (r & 7);
    gload16(Qp + (size_t)r * E_ + c * 8, (char*)Qlds + w * 1024);
  }
#pragma unroll
  for (int i = 0; i < 16; i++) {
    int ci = w * 16 + i;
    int r = ci * 8 + (l >> 3), c = (l & 7) ^ (r & 7);
    gload16(Kp + (size_t)r * E_ + c * 8, (char*)KV + ci * 1024);
  }
  __syncthreads();   // full drain: K,Q in LDS

  s16x8 af[2][2];
#pragma unroll
  for (int fm = 0; fm < 2; fm++)
#pragma unroll
    for (int kk = 0; kk < 2; kk++) {
      int r = rh * 32 + fm * 16 + rl, ch = kk * 4 + kg;
      af[fm][kk] = *(const s16x8*)((const char*)Qlds + r * 128 + ((ch ^ (r & 7)) * 16));
    }

  f32x4 acc[2][16];
#pragma unroll
  for (int fm = 0; fm < 2; fm++)
#pragma unroll
    for (int ct = 0; ct < 16; ct++)
#pragma unroll
      for (int j = 0; j < 4; j++) acc[fm][ct][j] = 0.f;

  // ---- QK^T: no barriers, K resident ----
#pragma unroll
  for (int ct = 0; ct < 16; ct++) {
    s16x8 bf[2];
#pragma unroll
    for (int kk = 0; kk < 2; kk++) {
      int r = ct * 64 + cq * 16 + rl, ch = kk * 4 + kg;
      bf[kk] = *(const s16x8*)((const char*)KV + r * 128 + ((ch ^ (r & 7)) * 16));
    }
#pragma unroll
    for (int fm = 0; fm < 2; fm++)
#pragma unroll
      for (int kk = 0; kk < 2; kk++)
        acc[fm][ct] = __builtin_amdgcn_mfma_f32_16x16x32_bf16(af[fm][kk], bf[kk], acc[fm][ct], 0, 0, 0);
  }
  __syncthreads();   // all K reads done -> safe to overwrite KV with V

  // ---- issue FULL V^T panel load (stays in flight through softmax) ----
#pragma unroll
  for (int i = 0; i < 16; i++) {
    int ci = w * 16 + i;
    int e = ci >> 1, hf = ci & 1;
    int c = ((hf * 64 + l) & ~7) | ((l & 7) ^ (e & 7));
    gload16(Vp + (size_t)e * S_ + c * 8, (char*)KV + e * 2048 + hf * 1024);
  }

  // ---- x prefetch into registers (lands under softmax; epilogue = pure stores) ----
  int mh2 = w >> 1, nh2 = w & 1;
  int h = hb >> 3, bb = hb & 7;
  float xv[2][4];
#pragma unroll
  for (int fn = 0; fn < 2; fn++)
#pragma unroll
    for (int j = 0; j < 4; j++) {
      int mq = m0 + mh2 * 16 + kg * 4 + j;
      int e = h * 64 + nh2 * 32 + fn * 16 + rl;
      xv[fn][j] = x[(((size_t)bb * S_ + mq) << 10) + e];
    }

  // ---- softmax (scale 1/32 folded into exp); lgkm-only barriers keep V in flight ----
  float mx[2][4], Z[2][4], Z2[2][4];
#pragma unroll
  for (int fm = 0; fm < 2; fm++)
#pragma unroll
    for (int j = 0; j < 4; j++) {
      float m = acc[fm][0][j];
#pragma unroll
      for (int ct = 1; ct < 16; ct++) m = fmaxf(m, acc[fm][ct][j]);
#pragma unroll
      for (int off = 8; off >= 1; off >>= 1) m = fmaxf(m, __shfl_xor(m, off));
      mx[fm][j] = m;
    }
  if (rl == 0) {
#pragma unroll
    for (int fm = 0; fm < 2; fm++)
#pragma unroll
      for (int j = 0; j < 4; j++) red[0][rh * 32 + fm * 16 + kg * 4 + j][cq] = mx[fm][j];
  }
  BARL();
#pragma unroll
  for (int fm = 0; fm < 2; fm++)
#pragma unroll
    for (int j = 0; j < 4; j++) {
      f32x4 r4 = *(const f32x4*)&red[0][rh * 32 + fm * 16 + kg * 4 + j][0];
      mx[fm][j] = fmaxf(fmaxf(r4[0], r4[1]), fmaxf(r4[2], r4[3]));
    }
#pragma unroll
  for (int fm = 0; fm < 2; fm++)
#pragma unroll
    for (int j = 0; j < 4; j++) {
      float s = 0.f;
#pragma unroll
      for (int ct = 0; ct < 16; ct++) {
        float e = __expf((acc[fm][ct][j] - mx[fm][j]) * 0.03125f);
        acc[fm][ct][j] = e;
        s += e;
      }
#pragma unroll
      for (int off = 8; off >= 1; off >>= 1) s += __shfl_xor(s, off);
      Z[fm][j] = s;
    }
  if (rl == 0) {
#pragma unroll
    for (int fm = 0; fm < 2; fm++)
#pragma unroll
      for (int j = 0; j < 4; j++) red[1][rh * 32 + fm * 16 + kg * 4 + j][cq] = Z[fm][j];
  }
  BARL();
#pragma unroll
  for (int fm = 0; fm < 2; fm++)
#pragma unroll
    for (int j = 0; j < 4; j++) {
      f32x4 r4 = *(const f32x4*)&red[1][rh * 32 + fm * 16 + kg * 4 + j][0];
      Z[fm][j] = r4[0] + r4[1] + r4[2] + r4[3];
    }
  // threshold: keep e >= 0.001*Z (<=> p >= 0.001), re-sum survivors
#pragma unroll
  for (int fm = 0; fm < 2; fm++)
#pragma unroll
    for (int j = 0; j < 4; j++) {
      float thr = 0.001f * Z[fm][j];
      float s = 0.f;
#pragma unroll
      for (int ct = 0; ct < 16; ct++) {
        float e = acc[fm][ct][j];
        e = (e >= thr) ? e : 0.f;
        acc[fm][ct][j] = e;
        s += e;
      }
#pragma unroll
      for (int off = 8; off >= 1; off >>= 1) s += __shfl_xor(s, off);
      Z2[fm][j] = s;
    }
  if (rl == 0) {
#pragma unroll
    for (int fm = 0; fm < 2; fm++)
#pragma unroll
      for (int j = 0; j < 4; j++) red[2][rh * 32 + fm * 16 + kg * 4 + j][cq] = Z2[fm][j];
  }
  BARL();
#pragma unroll
  for (int fm = 0; fm < 2; fm++)
#pragma unroll
    for (int j = 0; j < 4; j++) {
      f32x4 r4 = *(const f32x4*)&red[2][rh * 32 + fm * 16 + kg * 4 + j][0];
      float z2 = r4[0] + r4[1] + r4[2] + r4[3];
      float inv = 1.f / (z2 + 1e-12f * Z[fm][j]);  // == p/(sum_kept_p + 1e-12)
#pragma unroll
      for (int ct = 0; ct < 16; ct++) acc[fm][ct][j] *= inv;
    }

  // ---- retire V (and xv) loads; att stores issued AFTER so they're never waited ----
  asm volatile("s_waitcnt vmcnt(0)" ::: "memory");
  __builtin_amdgcn_sched_barrier(0);

  // ---- att fp32 stores: fire-and-forget under the whole PV loop ----
  float* attp = att + ((size_t)hb << 20) + ((size_t)m0 << 10);
#pragma unroll
  for (int fm = 0; fm < 2; fm++)
#pragma unroll
    for (int j = 0; j < 4; j++) {
      int m = rh * 32 + fm * 16 + kg * 4 + j;
#pragma unroll
      for (int ct = 0; ct < 16; ct++)
        attp[((size_t)m << 10) + ct * 64 + cq * 16 + rl] = acc[fm][ct][j];
    }

  // ---- PV, software-pipelined: write Ab[ct+1] between ct's ds_reads and MFMAs ----
  f32x4 acc2[2];
#pragma unroll
  for (int fn = 0; fn < 2; fn++)
#pragma unroll
    for (int j = 0; j < 4; j++) acc2[fn][j] = 0.f;

  // prologue: publish chunk 0
#pragma unroll
  for (int fm = 0; fm < 2; fm++)
#pragma unroll
    for (int j = 0; j < 4; j++) {
      int m = rh * 32 + fm * 16 + kg * 4 + j;
      int tl = cq * 16 + rl;
      *(u16*)((char*)Ab[0] + m * 128 + (((tl >> 3) ^ (m & 7)) * 16) + (tl & 7) * 2)
          = f2b(acc[fm][0][j]);
    }
  BARL();

#pragma unroll
  for (int ct = 0; ct < 16; ct++) {
    s16x8 a2[2], b2[2][2];
#pragma unroll
    for (int kk = 0; kk < 2; kk++) {
      int ch = kk * 4 + kg;
      int rA = mh2 * 16 + rl;
      a2[kk] = *(const s16x8*)((const char*)Ab[ct & 1] + rA * 128 + ((ch ^ (rA & 7)) * 16));
#pragma unroll
      for (int fn = 0; fn < 2; fn++) {
        int e = nh2 * 32 + fn * 16 + rl;
        b2[fn][kk] = *(const s16x8*)((const char*)KV + e * 2048 + ct * 128 + ((ch ^ (e & 7)) * 16));
      }
    }
    if (ct < 15) {  // stage next chunk into the other buffer
#pragma unroll
      for (int fm = 0; fm < 2; fm++)
#pragma unroll
        for (int j = 0; j < 4; j++) {
          int m = rh * 32 + fm * 16 + kg * 4 + j;
          int tl = cq * 16 + rl;
          *(u16*)((char*)Ab[(ct + 1) & 1] + m * 128 + (((tl >> 3) ^ (m & 7)) * 16) + (tl & 7) * 2)
              = f2b(acc[fm][ct + 1][j]);
        }
    }
    __builtin_amdgcn_s_setprio(1);
#pragma unroll
    for (int fn = 0; fn < 2; fn++)
#pragma unroll
      for (int kk = 0; kk < 2; kk++)
        acc2[fn] = __builtin_amdgcn_mfma_f32_16x16x32_bf16(a2[kk], b2[fn][kk], acc2[fn], 0, 0, 0);
    __builtin_amdgcn_s_setprio(0);
    BARL();
  }

  // ---- epilogue: out = xv + latent (pure stores) ----
#pragma unroll
  for (int fn = 0; fn < 2; fn++)
#pragma unroll
    for (int j = 0; j < 4; j++) {
      int mq = m0 + mh2 * 16 + kg * 4 + j;
      int e = h * 64 + nh2 * 32 + fn * 16 + rl;
      size_t idx = (((size_t)bb * S_ + mq) << 10) + e;
      out[idx] = xv[fn][j] + acc2[fn][j];
    }
}

extern "C" void kernel_launch(void* const* d_in, const int* in_sizes, int n_in,
                              void* d_out, int out_size, void* d_ws, size_t ws_size,
                              hipStream_t stream) {
  const float* x  = (const float*)d_in[0];
  const float* Wq = (const float*)d_in[1];
  const float* bq = (const float*)d_in[2];
  const float* Wk = (const float*)d_in[3];
  const float* bk = (const float*)d_in[4];
  const float* Wv = (const float*)d_in[5];
  const float* bv = (const float*)d_in[6];
  float* xres = (float*)d_out;
  float* att  = xres + (size_t)B_ * S_ * D_;

  char* ws = (char*)d_ws;
  u16* xb  = (u16*)(ws);                  // 16 MB
  u16* wbt = (u16*)(ws + 16777216);       //  6 MB
  u16* Qb  = (u16*)(ws + 23068672);       // 16 MB
  u16* Kb  = (u16*)(ws + 39845888);       // 16 MB
  u16* Vt  = (u16*)(ws + 56623104);       // 16 MB, [h][b][e][s]

  k_prep  <<<dim3(4864), dim3(256), 0, stream>>>(x, xb, Wq, Wk, Wv, wbt);
  k_qkv   <<<dim3(1536), dim3(256), 0, stream>>>(xb, wbt, bq, bk, bv, Qb, Kb, Vt);
  f_attn  <<<dim3(2048), dim3(512), 0, stream>>>(Qb, Kb, Vt, x, att, xres);
}